// Round 1
// baseline (163.553 us; speedup 1.0000x reference)
//
#include <hip/hip_runtime.h>
#include <hip/hip_bf16.h>

#define BATCH 16384
#define MAX_ITEMS 200
#define TOTAL (BATCH * MAX_ITEMS)

// ---------------------------------------------------------------------------
// Kernel A: per-user precompute. One 64-lane wave per user.
// Computes the four 64->4 projections via wave shuffle-reduction, then folds
// them into:
//   gu[j]   = Wf[j]*gmf_user[j] + Wf[4+j]*gmf_noise[j]        (j = 0..3)
//   base[k] = bn[k] + Wn[k][0:4].ncf_user + Wn[k][4:8].ncf_noise  (k = 0..7)
// Stores 12 floats per user into ws.
// ---------------------------------------------------------------------------
__global__ __launch_bounds__(256) void user_precompute(
    const float* __restrict__ noise,
    const float* __restrict__ uemb,
    const float* __restrict__ W0, const float* __restrict__ b0,
    const float* __restrict__ W1, const float* __restrict__ b1,
    const float* __restrict__ W2, const float* __restrict__ b2,
    const float* __restrict__ W3, const float* __restrict__ b3,
    const float* __restrict__ Wn, const float* __restrict__ bn,
    const float* __restrict__ Wf,
    float* __restrict__ ws)
{
    int wid  = (blockIdx.x * blockDim.x + threadIdx.x) >> 6;  // user index
    int lane = threadIdx.x & 63;
    if (wid >= BATCH) return;

    const float* ur = uemb  + (size_t)wid * 128;
    const float* nr = noise + (size_t)wid * 128;
    float e0 = ur[lane];        // gmf_user input   (init_user_emb[:, :64])
    float e1 = ur[64 + lane];   // ncf_user input   (init_user_emb[:, 64:])
    float n0 = nr[lane];        // gmf_noise input  (noise[:, :64])
    float n1 = nr[64 + lane];   // ncf_noise input  (noise[:, 64:])

    float gu[4], nu[4], gn[4], nn[4];
#pragma unroll
    for (int j = 0; j < 4; ++j) {
        float a = e0 * W0[j * 64 + lane];
        float b = e1 * W1[j * 64 + lane];
        float c = n0 * W2[j * 64 + lane];
        float d = n1 * W3[j * 64 + lane];
#pragma unroll
        for (int m = 1; m < 64; m <<= 1) {
            a += __shfl_xor(a, m, 64);
            b += __shfl_xor(b, m, 64);
            c += __shfl_xor(c, m, 64);
            d += __shfl_xor(d, m, 64);
        }
        gu[j] = a + b0[j];
        nu[j] = b + b1[j];
        gn[j] = c + b2[j];
        nn[j] = d + b3[j];
    }

    if (lane == 0) {
        float* o = ws + (size_t)wid * 12;
#pragma unroll
        for (int j = 0; j < 4; ++j)
            o[j] = Wf[j] * gu[j] + Wf[4 + j] * gn[j];
#pragma unroll
        for (int k = 0; k < 8; ++k) {
            float t = bn[k];
#pragma unroll
            for (int i = 0; i < 4; ++i)
                t += Wn[k * 12 + i] * nu[i] + Wn[k * 12 + 4 + i] * nn[i];
            o[4 + k] = t;
        }
    }
}

// ---------------------------------------------------------------------------
// Kernel B: per-(user, item) scoring. One thread per flat element.
//   score = bf + dot(gmf_item, gu)
//         + sum_k Wf[8+k] * relu(base[k] + Wn[k][8:12].ncf_item)
//   out = p * rating + score
// ---------------------------------------------------------------------------
__global__ __launch_bounds__(256) void score_kernel(
    const float* __restrict__ ratings,
    const int*   __restrict__ ids,
    const float* __restrict__ gmf_emb,
    const float* __restrict__ ncf_emb,
    const float* __restrict__ Wn,
    const float* __restrict__ Wf,
    const float* __restrict__ bf,
    const float* __restrict__ p,
    const float* __restrict__ ws,
    float* __restrict__ out)
{
    __shared__ float sWn[32];  // Wn[k][8+i], k-major
    __shared__ float sWf[8];   // Wf[8+k]
    __shared__ float sBF, sP;

    int tid = threadIdx.x;
    if (tid < 32)      sWn[tid] = Wn[(tid >> 2) * 12 + 8 + (tid & 3)];
    else if (tid < 40) sWf[tid - 32] = Wf[8 + (tid - 32)];
    else if (tid == 40) sBF = bf[0];
    else if (tid == 41) sP  = p[0];
    __syncthreads();

    int idx = blockIdx.x * blockDim.x + tid;
    if (idx >= TOTAL) return;

    int b = idx / MAX_ITEMS;            // const-divisor -> magic mul

    float rating = ratings[idx];
    int   id     = ids[idx];

    const float4 gi = *reinterpret_cast<const float4*>(gmf_emb + (size_t)id * 4);
    const float4 ni = *reinterpret_cast<const float4*>(ncf_emb + (size_t)id * 4);

    const float* u = ws + (size_t)b * 12;
    float acc = sBF
              + gi.x * u[0] + gi.y * u[1] + gi.z * u[2] + gi.w * u[3];

#pragma unroll
    for (int k = 0; k < 8; ++k) {
        float t = u[4 + k]
                + sWn[k * 4 + 0] * ni.x
                + sWn[k * 4 + 1] * ni.y
                + sWn[k * 4 + 2] * ni.z
                + sWn[k * 4 + 3] * ni.w;
        acc += sWf[k] * fmaxf(t, 0.0f);
    }

    out[idx] = sP * rating + acc;
}

extern "C" void kernel_launch(void* const* d_in, const int* in_sizes, int n_in,
                              void* d_out, int out_size, void* d_ws, size_t ws_size,
                              hipStream_t stream) {
    const float* ratings = (const float*)d_in[0];
    const int*   ids     = (const int*)  d_in[1];
    const float* noise   = (const float*)d_in[2];
    const float* uemb    = (const float*)d_in[3];
    const float* gmf_emb = (const float*)d_in[4];
    const float* ncf_emb = (const float*)d_in[5];
    const float* W0 = (const float*)d_in[6];
    const float* b0 = (const float*)d_in[7];
    const float* W1 = (const float*)d_in[8];
    const float* b1 = (const float*)d_in[9];
    const float* W2 = (const float*)d_in[10];
    const float* b2 = (const float*)d_in[11];
    const float* W3 = (const float*)d_in[12];
    const float* b3 = (const float*)d_in[13];
    const float* Wn = (const float*)d_in[14];
    const float* bn = (const float*)d_in[15];
    const float* Wf = (const float*)d_in[16];
    const float* bf = (const float*)d_in[17];
    const float* p  = (const float*)d_in[18];
    float* out = (float*)d_out;
    float* ws  = (float*)d_ws;   // 16384 * 12 floats = 786 KB

    // Kernel A: 16384 users, one wave each, 4 waves per block.
    user_precompute<<<BATCH / 4, 256, 0, stream>>>(
        noise, uemb, W0, b0, W1, b1, W2, b2, W3, b3, Wn, bn, Wf, ws);

    // Kernel B: one thread per (user, item).
    score_kernel<<<(TOTAL + 255) / 256, 256, 0, stream>>>(
        ratings, ids, gmf_emb, ncf_emb, Wn, Wf, bf, p, ws, out);
}